// Round 5
// baseline (81.992 us; speedup 1.0000x reference)
//
#include <hip/hip_runtime.h>
#include <hip/hip_bf16.h>

// Chamfer loss, N=8, V=4096, C=3, fp32.
// loss = (sum over all 2*N*V points of sqrt(min squared dist to other set)) / (N*V)
//
// Round 5: 2 kernels, no init, no workspace poison dependence.
//  - chamfer_main: 1024 blocks = (dir, n, vb, yc). Stages a 128-point B-chunk
//    in LDS as float4 (coords+norm, 2 KB). PX=8 A-points per thread in regs;
//    inner loop = 1 broadcast ds_read_b128 per 28 VALU ops, 3.5 ops/pair
//    (6 fma + 1 min3 per 2 B-points; A-norm hoisted out of the min).
//    Writes per-chunk minima to 32 planes (plain coalesced stores).
//    Block 0 also zeroes d_out (reduce runs after main in stream order).
//  - chamfer_reduce: 256 blocks; min over 32 planes, sqrt, block-sum,
//    one atomicAdd per block into d_out.

#define N_BATCH 8
#define V 4096
#define TPB 256
#define PX 8                   // A-points per thread
#define VBLK (TPB * PX)        // 2048 A-points per block
#define NVB (V / VBLK)         // 2
#define NYC 32                 // B-chunks
#define YC (V / NYC)           // 128
#define NPTS (N_BATCH * V)     // 32768 per direction
#define TOTPTS (2 * NPTS)      // 65536
#define NBLK_MAIN (2 * N_BATCH * NVB * NYC)  // 1024
#define NBLK_RED (TOTPTS / TPB)              // 256

__global__ __launch_bounds__(TPB) void chamfer_main(const float* __restrict__ x,
                                                    const float* __restrict__ y,
                                                    float* __restrict__ wmin2,
                                                    float* __restrict__ out) {
    __shared__ float4 sb[YC];   // 2 KB: (bx, by, bz, ||b||^2)

    if (blockIdx.x == 0 && threadIdx.x == 0) out[0] = 0.0f;

    int bid = blockIdx.x;
    int yc  = bid & (NYC - 1);        // 0..31
    int vb  = (bid >> 5) & (NVB - 1); // 0..1
    int n   = (bid >> 6) & 7;         // 0..7
    int dir = bid >> 9;               // 0: A=x,B=y ; 1: A=y,B=x

    const float* A  = dir ? y : x;
    const float* B  = dir ? x : y;
    const float* Ab = A + (size_t)n * (V * 3);
    const float* Bb = B + (size_t)n * (V * 3) + (size_t)yc * (YC * 3);

    // Stage B-chunk into LDS
    if (threadIdx.x < YC) {
        int i = threadIdx.x;
        float b0 = Bb[3 * i + 0];
        float b1 = Bb[3 * i + 1];
        float b2 = Bb[3 * i + 2];
        sb[i] = make_float4(b0, b1, b2, b0 * b0 + b1 * b1 + b2 * b2);
    }

    // Per-thread A-points (pre-scaled by -2; norm hoisted out of the min)
    float nx0[PX], nx1[PX], nx2[PX], pxs[PX], m[PX];
    const int pbase = vb * VBLK + threadIdx.x;
#pragma unroll
    for (int p = 0; p < PX; ++p) {
        const float* ap = Ab + 3 * (pbase + p * TPB);
        float a0 = ap[0], a1 = ap[1], a2 = ap[2];
        nx0[p] = -2.0f * a0;
        nx1[p] = -2.0f * a1;
        nx2[p] = -2.0f * a2;
        pxs[p] = a0 * a0 + a1 * a1 + a2 * a2;
        m[p] = 1e30f;
    }

    __syncthreads();

    // 3.5 VALU ops/pair (6 fma + 1 min3 per 2 B-points);
    // 1 broadcast ds_read_b128 per 28 VALU ops.
#pragma unroll 4
    for (int j = 0; j < YC; j += 2) {
        float4 b0 = sb[j];
        float4 b1 = sb[j + 1];
#pragma unroll
        for (int p = 0; p < PX; ++p) {
            float t0 = fmaf(nx0[p], b0.x, b0.w);
            t0 = fmaf(nx1[p], b0.y, t0);
            t0 = fmaf(nx2[p], b0.z, t0);
            float t1 = fmaf(nx0[p], b1.x, b1.w);
            t1 = fmaf(nx1[p], b1.y, t1);
            t1 = fmaf(nx2[p], b1.z, t1);
            m[p] = fminf(fminf(m[p], t0), t1);  // -> v_min3_f32
        }
    }

    // Plane layout: wmin2[yc][gp], gp = dir*32768 + n*4096 + vb*2048 + lane
    float* wout = wmin2 + (size_t)yc * TOTPTS + dir * NPTS + n * V + pbase;
#pragma unroll
    for (int p = 0; p < PX; ++p) {
        wout[p * TPB] = m[p] + pxs[p];   // full squared distance (may be ~-eps)
    }
}

__global__ __launch_bounds__(TPB) void chamfer_reduce(const float* __restrict__ wmin2,
                                                      float* __restrict__ out) {
    __shared__ float swsum[TPB / 64];
    int gp = blockIdx.x * TPB + threadIdx.x;
    float m = wmin2[gp];
#pragma unroll
    for (int yc = 1; yc < NYC; ++yc) {
        m = fminf(m, wmin2[(size_t)yc * TOTPTS + gp]);
    }
    float d = sqrtf(fmaxf(m, 0.0f));
    for (int off = 32; off > 0; off >>= 1) d += __shfl_down(d, off);
    int lane = threadIdx.x & 63, wid = threadIdx.x >> 6;
    if (lane == 0) swsum[wid] = d;
    __syncthreads();
    if (threadIdx.x == 0) {
        float blocksum = swsum[0] + swsum[1] + swsum[2] + swsum[3];
        atomicAdd(out, blocksum * (1.0f / (float)NPTS));
    }
}

extern "C" void kernel_launch(void* const* d_in, const int* in_sizes, int n_in,
                              void* d_out, int out_size, void* d_ws, size_t ws_size,
                              hipStream_t stream) {
    const float* x = (const float*)d_in[0];
    const float* y = (const float*)d_in[1];
    float* out = (float*)d_out;
    float* wmin2 = (float*)d_ws;   // 32 planes * 65536 floats = 8 MB

    chamfer_main<<<NBLK_MAIN, TPB, 0, stream>>>(x, y, wmin2, out);
    chamfer_reduce<<<NBLK_RED, TPB, 0, stream>>>(wmin2, out);
}